// Round 1
// baseline (251.296 us; speedup 1.0000x reference)
//
#include <hip/hip_runtime.h>

// One thread per 3-qubit state (8 complex amps fully in registers).
// amp index = 4*q0 + 2*q1 + q2.
// Circuit: H(q0),H(q1),RX(t0,q0),RX(t1,q1),CNOT(q0->q2). Gates on distinct
// qubits commute -> apply fused M(q) = RX(theta_q)*H per qubit:
//   M = k*[[c-is, c+is],[c-is, -(c+is)]], k = 1/sqrt(2)
//   => a' = p*a + q*b ; b' = p*a - q*b, p = k(c-is), q = k(c+is).
// All pairs are thread-local: q0 couples (j, j+4); q1 couples (j, j+2).
// CNOT (flip q2 where q0==1) is an index swap folded into the store.
// K=4 states per thread, all 16 float4 loads issued up-front for MLP.

__device__ __forceinline__ void state_compute_store(
    float4 fr0, float4 fr1, float4 fi0, float4 fi1,
    float kc0, float ks0, float kc1, float ks1,
    float4* __restrict__ o4, int s)
{
    float r[8]  = {fr0.x, fr0.y, fr0.z, fr0.w, fr1.x, fr1.y, fr1.z, fr1.w};
    float im[8] = {fi0.x, fi0.y, fi0.z, fi0.w, fi1.x, fi1.y, fi1.z, fi1.w};

    // --- fused H+RX on qubit 0: pairs (j, j+4) ---
    // p*a = (kc*ar + ks*ai) + i(kc*ai - ks*ar)
    // q*b = (kc*br - ks*bi) + i(kc*bi + ks*br)
#pragma unroll
    for (int j = 0; j < 4; ++j) {
        float ar = r[j], ai = im[j], br = r[j + 4], bi = im[j + 4];
        float par = kc0 * ar + ks0 * ai;
        float pai = kc0 * ai - ks0 * ar;
        float qbr = kc0 * br - ks0 * bi;
        float qbi = kc0 * bi + ks0 * br;
        r[j]      = par + qbr;  im[j]     = pai + qbi;
        r[j + 4]  = par - qbr;  im[j + 4] = pai - qbi;
    }

    // --- fused H+RX on qubit 1: pairs (j, j+2), j in {0,1,4,5} ---
#pragma unroll
    for (int t = 0; t < 4; ++t) {
        int j = (t & 1) + ((t & 2) << 1);  // 0,1,4,5
        float ar = r[j], ai = im[j], br = r[j + 2], bi = im[j + 2];
        float par = kc1 * ar + ks1 * ai;
        float pai = kc1 * ai - ks1 * ar;
        float qbr = kc1 * br - ks1 * bi;
        float qbi = kc1 * bi + ks1 * br;
        r[j]      = par + qbr;  im[j]     = pai + qbi;
        r[j + 2]  = par - qbr;  im[j + 2] = pai - qbi;
    }

    // --- CNOT(q0 ctrl, q2 tgt): out[4+2q1+q2] = amp[4+2q1+(1-q2)] ---
    // Output layout (B,8,2): interleaved real/imag, 64 B contiguous per state.
    o4[4 * s + 0] = make_float4(r[0], im[0], r[1], im[1]);
    o4[4 * s + 1] = make_float4(r[2], im[2], r[3], im[3]);
    o4[4 * s + 2] = make_float4(r[5], im[5], r[4], im[4]);
    o4[4 * s + 3] = make_float4(r[7], im[7], r[6], im[6]);
}

__global__ __launch_bounds__(256) void circuit_kernel(
    const float4* __restrict__ xr4,
    const float4* __restrict__ xi4,
    const float* __restrict__ theta,
    float4* __restrict__ o4,
    int S)  // S = B states
{
    constexpr int K = 4;
    const float k = 0.70710678118654752440f;

    float c0, s0v, c1, s1v;
    __sincosf(theta[0] * 0.5f, &s0v, &c0);
    __sincosf(theta[1] * 0.5f, &s1v, &c1);
    const float kc0 = k * c0, ks0 = k * s0v;
    const float kc1 = k * c1, ks1 = k * s1v;

    const int tid = blockIdx.x * blockDim.x + threadIdx.x;
    const int T   = gridDim.x * blockDim.x;

    if (tid + (K - 1) * T < S) {
        // Fast path: issue all 16 loads before any compute (MLP).
        float4 R0[K], R1[K], I0[K], I1[K];
#pragma unroll
        for (int m = 0; m < K; ++m) {
            int s = tid + m * T;
            R0[m] = xr4[2 * s];  R1[m] = xr4[2 * s + 1];
            I0[m] = xi4[2 * s];  I1[m] = xi4[2 * s + 1];
        }
#pragma unroll
        for (int m = 0; m < K; ++m) {
            state_compute_store(R0[m], R1[m], I0[m], I1[m],
                                kc0, ks0, kc1, ks1, o4, tid + m * T);
        }
    } else {
        // Tail (never taken when S % (K*blockDim*gridDim) == 0).
        for (int s = tid; s < S; s += T) {
            float4 r0 = xr4[2 * s], r1 = xr4[2 * s + 1];
            float4 i0 = xi4[2 * s], i1 = xi4[2 * s + 1];
            state_compute_store(r0, r1, i0, i1,
                                kc0, ks0, kc1, ks1, o4, s);
        }
    }
}

extern "C" void kernel_launch(void* const* d_in, const int* in_sizes, int n_in,
                              void* d_out, int out_size, void* d_ws, size_t ws_size,
                              hipStream_t stream) {
    const float4* xr4  = (const float4*)d_in[0];
    const float4* xi4  = (const float4*)d_in[1];
    const float* theta = (const float*)d_in[2];
    float4* o4 = (float4*)d_out;

    int S = in_sizes[0] / 8;  // states (same unit convention as prior kernel: N=in_sizes[0]/4 half-states)
    const int K = 4;
    int block = 256;
    int grid = (S + K * block - 1) / (K * block);  // 2048 blocks for B = 2^21
    circuit_kernel<<<grid, block, 0, stream>>>(xr4, xi4, theta, o4, S);
}

// Round 2
// 244.438 us; speedup vs baseline: 1.0281x; 1.0281x over previous
//
#include <hip/hip_runtime.h>

// One thread per 3-qubit state (8 complex amps fully in registers).
// amp index = 4*q0 + 2*q1 + q2.
// Circuit: H(q0),H(q1),RX(t0,q0),RX(t1,q1),CNOT(q0->q2). Gates on distinct
// qubits commute -> apply fused M(q) = RX(theta_q)*H per qubit:
//   M = k*[[c-is, c+is],[c-is, -(c+is)]], k = 1/sqrt(2)
//   => a' = p*a + q*b ; b' = p*a - q*b, p = k(c-is), q = k(c+is).
// All pairs thread-local: q0 couples (j, j+4); q1 couples (j, j+2).
// CNOT (flip q2 where q0==1) is an index swap folded into the store.
//
// K=1 state per thread, 8192 blocks: many short wave-generations so the HBM
// controller sees a steady-state MIX of reads (young waves) and writes
// (retiring waves). Round-1 lesson: grid == one residency generation
// phase-serializes the full read stream before the write stream (92 us).

__global__ __launch_bounds__(256) void circuit_kernel(
    const float4* __restrict__ xr4,
    const float4* __restrict__ xi4,
    const float* __restrict__ theta,
    float4* __restrict__ o4,
    int S)  // S = B states
{
    const int s = blockIdx.x * blockDim.x + threadIdx.x;
    if (s >= S) return;

    const float k = 0.70710678118654752440f;
    float c0, s0v, c1, s1v;
    __sincosf(theta[0] * 0.5f, &s0v, &c0);
    __sincosf(theta[1] * 0.5f, &s1v, &c1);
    const float kc0 = k * c0, ks0 = k * s0v;
    const float kc1 = k * c1, ks1 = k * s1v;

    // 4 x 16B loads, lane-stride 32B within each array (pairwise line-dense).
    float4 fr0 = xr4[2 * s], fr1 = xr4[2 * s + 1];
    float4 fi0 = xi4[2 * s], fi1 = xi4[2 * s + 1];

    float r[8]  = {fr0.x, fr0.y, fr0.z, fr0.w, fr1.x, fr1.y, fr1.z, fr1.w};
    float im[8] = {fi0.x, fi0.y, fi0.z, fi0.w, fi1.x, fi1.y, fi1.z, fi1.w};

    // --- fused H+RX on qubit 0: pairs (j, j+4) ---
    // p*a = (kc*ar + ks*ai) + i(kc*ai - ks*ar)
    // q*b = (kc*br - ks*bi) + i(kc*bi + ks*br)
#pragma unroll
    for (int j = 0; j < 4; ++j) {
        float ar = r[j], ai = im[j], br = r[j + 4], bi = im[j + 4];
        float par = kc0 * ar + ks0 * ai;
        float pai = kc0 * ai - ks0 * ar;
        float qbr = kc0 * br - ks0 * bi;
        float qbi = kc0 * bi + ks0 * br;
        r[j]      = par + qbr;  im[j]     = pai + qbi;
        r[j + 4]  = par - qbr;  im[j + 4] = pai - qbi;
    }

    // --- fused H+RX on qubit 1: pairs (j, j+2), j in {0,1,4,5} ---
#pragma unroll
    for (int t = 0; t < 4; ++t) {
        int j = (t & 1) + ((t & 2) << 1);  // 0,1,4,5
        float ar = r[j], ai = im[j], br = r[j + 2], bi = im[j + 2];
        float par = kc1 * ar + ks1 * ai;
        float pai = kc1 * ai - ks1 * ar;
        float qbr = kc1 * br - ks1 * bi;
        float qbi = kc1 * bi + ks1 * br;
        r[j]      = par + qbr;  im[j]     = pai + qbi;
        r[j + 2]  = par - qbr;  im[j + 2] = pai - qbi;
    }

    // --- CNOT(q0 ctrl, q2 tgt): out[4+2q1+q2] = amp[4+2q1+(1-q2)] ---
    // Output layout (B,8,2): interleaved real/imag, 64 B contiguous per state.
    o4[4 * s + 0] = make_float4(r[0], im[0], r[1], im[1]);
    o4[4 * s + 1] = make_float4(r[2], im[2], r[3], im[3]);
    o4[4 * s + 2] = make_float4(r[5], im[5], r[4], im[4]);
    o4[4 * s + 3] = make_float4(r[7], im[7], r[6], im[6]);
}

extern "C" void kernel_launch(void* const* d_in, const int* in_sizes, int n_in,
                              void* d_out, int out_size, void* d_ws, size_t ws_size,
                              hipStream_t stream) {
    const float4* xr4  = (const float4*)d_in[0];
    const float4* xi4  = (const float4*)d_in[1];
    const float* theta = (const float*)d_in[2];
    float4* o4 = (float4*)d_out;

    int S = in_sizes[0] / 32;  // bytes -> states (8 floats/state)... see note
    // in_sizes[] convention from prior rounds: in_sizes[0]/4 == 2B half-states
    // (i.e., units of floats). Keep identical arithmetic: S = floats/8.
    S = (in_sizes[0] / 4) / 2;  // half-states / 2 == states (matches round-1 S)
    int block = 256;
    int grid = (S + block - 1) / block;  // 8192 blocks for B = 2^21
    circuit_kernel<<<grid, block, 0, stream>>>(xr4, xi4, theta, o4, S);
}

// Round 3
// 234.574 us; speedup vs baseline: 1.0713x; 1.0421x over previous
//
#include <hip/hip_runtime.h>

// Two threads per 3-qubit state. Thread u: state s = u>>1, half h = u&1,
// holding amps 4h..4h+3 (amp index = 4*q0+2*q1+q2, so h == q0).
// Circuit: H(q0),H(q1),RX(t0,q0),RX(t1,q1),CNOT(q0->q2). Gates on distinct
// qubits commute -> fused M(q) = RX(theta_q)*H per qubit:
//   M = k*[[c-is, c+is],[c-is, -(c+is)]], k=1/sqrt(2)
//   => a' = p*a + q*b ; b' = p*a - q*b, p=k(c-is), q=k(c+is).
// q0 gate couples the thread pair: multiply local half by (h?q:p), exchange
// via __shfl_xor(.,1) (adjacent-lane DPP), combine. q1 gate pairs (j,j+2)
// locally; CNOT (flip q2 when q0==1) is an index swap folded into the
// output-pair construction.
//
// Round-2 lesson: non-unit lane strides amplify 64B-line requests in TA/TCP
// (32B-stride stores = 2x, 64B-stride = 4x) and cap effective BW at
// 6.3/amplification TB/s. This version makes EVERY global access unit-stride:
// loads are xr4[u]/xi4[u] (16B/lane contiguous); stores go through an 8KB LDS
// transpose so each store instruction writes 256 contiguous float4.

__global__ __launch_bounds__(256) void circuit_kernel(
    const float4* __restrict__ xr4,
    const float4* __restrict__ xi4,
    const float* __restrict__ theta,
    float4* __restrict__ o4,
    int N)  // N = 2*B half-states; N % 256 == 0 (B is a power of two)
{
    __shared__ float4 buf[512];
    const int tid = threadIdx.x;
    const int u = blockIdx.x * 256 + tid;
    const int h = u & 1;
    const float k = 0.70710678118654752440f;

    float c0, s0, c1, s1;
    __sincosf(theta[0] * 0.5f, &s0, &c0);
    __sincosf(theta[1] * 0.5f, &s1, &c1);

    // q0 multiplier for this lane: p for h=0, q for h=1
    const float mr = k * c0;
    const float mi = h ? (k * s0) : (-k * s0);

    // Perfectly coalesced loads: 16 B/lane, lane-contiguous.
    float4 fr = xr4[u];
    float4 fi = xi4[u];
    float ar[4] = {fr.x, fr.y, fr.z, fr.w};
    float ai[4] = {fi.x, fi.y, fi.z, fi.w};

    // --- fused H+RX on qubit 0 (couples thread pair) ---
    float lr[4], li[4], pr[4], pi[4];
#pragma unroll
    for (int j = 0; j < 4; ++j) {
        lr[j] = mr * ar[j] - mi * ai[j];
        li[j] = mr * ai[j] + mi * ar[j];
    }
#pragma unroll
    for (int j = 0; j < 4; ++j) {
        pr[j] = __shfl_xor(lr[j], 1, 64);
        pi[j] = __shfl_xor(li[j], 1, 64);
    }
#pragma unroll
    for (int j = 0; j < 4; ++j) {
        // h=0: local(p*a) + partner(q*b);  h=1: partner(p*a) - local(q*b)
        ar[j] = h ? (pr[j] - lr[j]) : (lr[j] + pr[j]);
        ai[j] = h ? (pi[j] - li[j]) : (li[j] + pi[j]);
    }

    // --- fused H+RX on qubit 1: pairs (j, j+2), thread-local ---
    const float p1r = k * c1, p1i = -k * s1;
    const float q1r = k * c1, q1i = k * s1;
#pragma unroll
    for (int j = 0; j < 2; ++j) {
        float xr_ = p1r * ar[j]     - p1i * ai[j];
        float xi_ = p1r * ai[j]     + p1i * ar[j];
        float yr_ = q1r * ar[j + 2] - q1i * ai[j + 2];
        float yi_ = q1r * ai[j + 2] + q1i * ar[j + 2];
        ar[j]     = xr_ + yr_;  ai[j]     = xi_ + yi_;
        ar[j + 2] = xr_ - yr_;  ai[j + 2] = xi_ - yi_;
    }

    // --- CNOT (q0 ctrl, q2 tgt): h==1 swaps j0<->j1, j2<->j3 ---
    // Output slot for thread u: o4[2u] and o4[2u+1] (64B/state, r/i interleaved).
    // Stage both float4 in LDS, then store block-contiguous (unit stride).
    int a = h ? 1 : 0, b = h ? 0 : 1, c = h ? 3 : 2, d = h ? 2 : 3;
    buf[2 * tid]     = make_float4(ar[a], ai[a], ar[b], ai[b]);
    buf[2 * tid + 1] = make_float4(ar[c], ai[c], ar[d], ai[d]);
    __syncthreads();

    float4* __restrict__ dst = o4 + (size_t)2 * blockIdx.x * 256;
    dst[tid]       = buf[tid];
    dst[tid + 256] = buf[tid + 256];
}

extern "C" void kernel_launch(void* const* d_in, const int* in_sizes, int n_in,
                              void* d_out, int out_size, void* d_ws, size_t ws_size,
                              hipStream_t stream) {
    const float4* xr4  = (const float4*)d_in[0];
    const float4* xi4  = (const float4*)d_in[1];
    const float* theta = (const float*)d_in[2];
    float4* o4 = (float4*)d_out;

    int N = in_sizes[0] / 4;  // B*8 floats / 4 = 2B half-states (N % 256 == 0)
    int block = 256;
    int grid = (N + block - 1) / block;  // 16384 blocks for B = 2^21
    circuit_kernel<<<grid, block, 0, stream>>>(xr4, xi4, theta, o4, N);
}